// Round 3
// baseline (108.844 us; speedup 1.0000x reference)
//
#include <hip/hip_runtime.h>

#define BINS 256
#define BC_N 24   // B*C = 8*3
#define C_N  3

// ---------------------------------------------------------------------------
// Kernel 1: per-row 256-bin histograms of dst and ref.
// grid = (chunks, 24 rows, 2 images), block = 256.
// bin = floor(x * 256) clipped to [0,255] (trunc == floor for x >= 0).
// ---------------------------------------------------------------------------
__global__ __launch_bounds__(256) void hm_hist(const float* __restrict__ dst,
                                               const float* __restrict__ refp,
                                               unsigned int* __restrict__ hist,
                                               int n4_per_row) {
    __shared__ unsigned int sh[BINS];
    const int t = threadIdx.x;
    sh[t] = 0u;
    __syncthreads();

    const int row = blockIdx.y;
    const float* img = blockIdx.z ? refp : dst;
    const float4* p = reinterpret_cast<const float4*>(img) + (size_t)row * n4_per_row;

    for (int i = blockIdx.x * blockDim.x + t; i < n4_per_row; i += gridDim.x * blockDim.x) {
        float4 v = p[i];
        int b0 = min(max((int)(v.x * 256.0f), 0), BINS - 1);
        int b1 = min(max((int)(v.y * 256.0f), 0), BINS - 1);
        int b2 = min(max((int)(v.z * 256.0f), 0), BINS - 1);
        int b3 = min(max((int)(v.w * 256.0f), 0), BINS - 1);
        atomicAdd(&sh[b0], 1u);
        atomicAdd(&sh[b1], 1u);
        atomicAdd(&sh[b2], 1u);
        atomicAdd(&sh[b3], 1u);
    }
    __syncthreads();

    unsigned int* g = hist + ((size_t)blockIdx.z * BC_N + row) * BINS;
    unsigned int v = sh[t];
    if (v) atomicAdd(&g[t], v);
}

// ---------------------------------------------------------------------------
// Kernel 2: per row, normalize -> CDF (exact fp32: all partials are dyadic
// with numerator < 2^24) -> transfer table via parallelized two-pointer:
//   s_i = searchsorted(cdf_ref, cdf_dst[i])  (monotone in i)
//   before first failure: table[i] = max(1, s_i)
//   first i with !( cand<=255 && d>=cdf_ref[cand-1] ) poisons all i' >= i to 255
// table[0]=0, table[255]=255. lut = table / 255.0f.
// grid = 24 blocks, block = 256 (thread t handles table index t).
// ---------------------------------------------------------------------------
__global__ __launch_bounds__(256) void hm_table(const unsigned int* __restrict__ hist,
                                                float* __restrict__ lut) {
    __shared__ float cnt_d[BINS], cnt_r[BINS];
    __shared__ float cdf_d[BINS], cdf_r[BINS];
    __shared__ int firstFail;

    const int r = blockIdx.x;
    const int t = threadIdx.x;

    cnt_d[t] = (float)hist[(size_t)r * BINS + t];
    cnt_r[t] = (float)hist[(size_t)(BC_N + r) * BINS + t];
    if (t == 0) firstFail = BINS;
    __syncthreads();

    if (t == 0) {
        // sequential sum + cumsum (matches np bit-for-bit; all ops exact here)
        float sd = 0.f, sr = 0.f;
        for (int i = 0; i < BINS; ++i) { sd += cnt_d[i]; sr += cnt_r[i]; }
        sd = fmaxf(sd, 1e-12f);
        sr = fmaxf(sr, 1e-12f);
        float cd = 0.f, cr = 0.f;
        for (int i = 0; i < BINS; ++i) {
            cd += cnt_d[i] / sd; cdf_d[i] = cd;
            cr += cnt_r[i] / sr; cdf_r[i] = cr;
        }
    }
    __syncthreads();

    int out;
    if (t == 0) {
        out = 0;
    } else {
        float d = cdf_d[t];
        // searchsorted 'left': smallest s in [0,256] with cdf_r[s] >= d
        int lo = 0, hi = BINS;
        while (lo < hi) {
            int m = (lo + hi) >> 1;
            if (cdf_r[m] < d) lo = m + 1; else hi = m;
        }
        int cand = lo > 1 ? lo : 1;
        bool ok = (cand <= BINS - 1) && (d >= cdf_r[cand - 1]);
        if (!ok) atomicMin(&firstFail, t);
        out = cand;
    }
    __syncthreads();

    if (t >= firstFail) out = BINS - 1;   // sticky j=256 -> 255 from first fail on
    if (t == BINS - 1) out = BINS - 1;    // table[:,255] = 255
    lut[(size_t)r * BINS + t] = (float)out / 255.0f;
}

// ---------------------------------------------------------------------------
// Kernel 3: apply LUT. Faithfully reproduces the reference's row_sel = b*c bug.
// pix = clip(trunc(dst*255), 0, 255). grid = (chunks, 24), block = 256.
// ---------------------------------------------------------------------------
__global__ __launch_bounds__(256) void hm_apply(const float* __restrict__ dst,
                                                const float* __restrict__ lut,
                                                float* __restrict__ out,
                                                int n4_per_row) {
    __shared__ float slut[BINS];
    const int bc = blockIdx.y;
    const int b = bc / C_N;
    const int c = bc - b * C_N;
    const int row = b * c;               // <-- preserved bug: b*c, not b*C+c
    const int t = threadIdx.x;

    slut[t] = lut[(size_t)row * BINS + t];
    __syncthreads();

    const float4* in4 = reinterpret_cast<const float4*>(dst) + (size_t)bc * n4_per_row;
    float4* out4 = reinterpret_cast<float4*>(out) + (size_t)bc * n4_per_row;

    for (int i = blockIdx.x * blockDim.x + t; i < n4_per_row; i += gridDim.x * blockDim.x) {
        float4 v = in4[i];
        float4 o;
        o.x = slut[min(max((int)(v.x * 255.0f), 0), BINS - 1)];
        o.y = slut[min(max((int)(v.y * 255.0f), 0), BINS - 1)];
        o.z = slut[min(max((int)(v.z * 255.0f), 0), BINS - 1)];
        o.w = slut[min(max((int)(v.w * 255.0f), 0), BINS - 1)];
        out4[i] = o;
    }
}

extern "C" void kernel_launch(void* const* d_in, const int* in_sizes, int n_in,
                              void* d_out, int out_size, void* d_ws, size_t ws_size,
                              hipStream_t stream) {
    const float* dst  = (const float*)d_in[0];
    const float* refp = (const float*)d_in[1];
    float* out = (float*)d_out;

    const int total = in_sizes[0];          // 8*3*1024*1024
    const int hw = total / BC_N;            // 1048576
    const int n4 = hw >> 2;                 // 262144 float4 per row

    // workspace layout: [hist_dst 24x256 u32][hist_ref 24x256 u32][lut 24x256 f32]
    unsigned int* hist = (unsigned int*)d_ws;
    float* lut = (float*)((char*)d_ws + (size_t)2 * BC_N * BINS * sizeof(unsigned int));

    hipMemsetAsync(d_ws, 0, (size_t)2 * BC_N * BINS * sizeof(unsigned int), stream);

    dim3 hg(32, BC_N, 2);
    hm_hist<<<hg, dim3(256), 0, stream>>>(dst, refp, hist, n4);

    hm_table<<<dim3(BC_N), dim3(256), 0, stream>>>(hist, lut);

    dim3 ag(64, BC_N);
    hm_apply<<<ag, dim3(256), 0, stream>>>(dst, lut, out, n4);
}

// Round 4
// 80.358 us; speedup vs baseline: 1.3545x; 1.3545x over previous
//
#include <hip/hip_runtime.h>

#define BINS 256
#define BC_N 24   // B*C = 8*3
#define C_N  3
#define NCOPY 16          // sub-histogram replicas (indexed by lane & 15)
#define HSTRIDE (NCOPY+1) // 17: bank = (17*bin + copy) % 32 -> copies of a bin on distinct banks

// ---------------------------------------------------------------------------
// Kernel 1: per-row 256-bin histograms of dst and ref.
// grid = (chunks, 24 rows, 2 images), block = 256.
// bin = floor(x * 256) clipped to [0,255] (trunc == floor for x >= 0).
// 16-way replicated LDS histograms kill same-bin atomic serialization.
// ---------------------------------------------------------------------------
__global__ __launch_bounds__(256) void hm_hist(const float* __restrict__ dst,
                                               const float* __restrict__ refp,
                                               unsigned int* __restrict__ hist,
                                               int n4_per_row) {
    __shared__ unsigned int sh[BINS * HSTRIDE];   // 17408 B
    const int t = threadIdx.x;
    for (int j = t; j < BINS * HSTRIDE; j += 256) sh[j] = 0u;
    __syncthreads();

    const int row = blockIdx.y;
    const float* img = blockIdx.z ? refp : dst;
    const float4* p = reinterpret_cast<const float4*>(img) + (size_t)row * n4_per_row;
    const int copy = t & (NCOPY - 1);
    const int gsz = gridDim.x * blockDim.x;

    #pragma unroll 4
    for (int i = blockIdx.x * blockDim.x + t; i < n4_per_row; i += gsz) {
        float4 v = p[i];
        int b0 = min(max((int)(v.x * 256.0f), 0), BINS - 1);
        int b1 = min(max((int)(v.y * 256.0f), 0), BINS - 1);
        int b2 = min(max((int)(v.z * 256.0f), 0), BINS - 1);
        int b3 = min(max((int)(v.w * 256.0f), 0), BINS - 1);
        atomicAdd(&sh[b0 * HSTRIDE + copy], 1u);
        atomicAdd(&sh[b1 * HSTRIDE + copy], 1u);
        atomicAdd(&sh[b2 * HSTRIDE + copy], 1u);
        atomicAdd(&sh[b3 * HSTRIDE + copy], 1u);
    }
    __syncthreads();

    unsigned int s = 0;
    #pragma unroll
    for (int c = 0; c < NCOPY; ++c) s += sh[t * HSTRIDE + c];

    unsigned int* g = hist + ((size_t)blockIdx.z * BC_N + row) * BINS;
    if (s) atomicAdd(&g[t], s);
}

// ---------------------------------------------------------------------------
// Kernel 2: per row, integer inclusive scan (exact: partials <= 2^20) ->
// CDF = cum / max(total,1e-12) (division by 2^20 exact, so bit-identical to
// np's sequential fp32 cumsum of count/total) -> transfer table via
// parallelized two-pointer:
//   s_i = searchsorted(cdf_ref, cdf_dst[i])  (monotone in i)
//   before first failure: table[i] = max(1, s_i)
//   first i with !(cand<=255 && d>=cdf_ref[cand-1]) poisons all i' >= i to 255
// table[0]=0, table[255]=255. lut = table / 255.0f.
// grid = 24 blocks, block = 256 (thread t handles table index t).
// ---------------------------------------------------------------------------
__global__ __launch_bounds__(256) void hm_table(const unsigned int* __restrict__ hist,
                                                float* __restrict__ lut) {
    __shared__ unsigned int sd[BINS], sr[BINS];
    __shared__ float cdf_d[BINS], cdf_r[BINS];
    __shared__ int firstFail;

    const int r = blockIdx.x;
    const int t = threadIdx.x;

    unsigned int xd = hist[(size_t)r * BINS + t];
    unsigned int xr = hist[(size_t)(BC_N + r) * BINS + t];
    if (t == 0) firstFail = BINS;
    sd[t] = xd; sr[t] = xr;
    __syncthreads();

    // Hillis-Steele inclusive scan (integer -> exact in any association)
    #pragma unroll
    for (int off = 1; off < BINS; off <<= 1) {
        unsigned int yd = (t >= off) ? sd[t - off] : 0u;
        unsigned int yr = (t >= off) ? sr[t - off] : 0u;
        __syncthreads();
        xd += yd; xr += yr;
        sd[t] = xd; sr[t] = xr;
        __syncthreads();
    }
    float totd = fmaxf((float)sd[BINS - 1], 1e-12f);
    float totr = fmaxf((float)sr[BINS - 1], 1e-12f);
    cdf_d[t] = (float)xd / totd;
    cdf_r[t] = (float)xr / totr;
    __syncthreads();

    int out;
    if (t == 0) {
        out = 0;
    } else {
        float d = cdf_d[t];
        // searchsorted 'left': smallest s in [0,256] with cdf_r[s] >= d
        int lo = 0, hi = BINS;
        while (lo < hi) {
            int m = (lo + hi) >> 1;
            if (cdf_r[m] < d) lo = m + 1; else hi = m;
        }
        int cand = lo > 1 ? lo : 1;
        bool ok = (cand <= BINS - 1) && (d >= cdf_r[cand - 1]);
        if (!ok) atomicMin(&firstFail, t);
        out = cand;
    }
    __syncthreads();

    if (t >= firstFail) out = BINS - 1;   // sticky j=256 -> 255 from first fail on
    if (t == BINS - 1) out = BINS - 1;    // table[:,255] = 255
    lut[(size_t)r * BINS + t] = (float)out / 255.0f;
}

// ---------------------------------------------------------------------------
// Kernel 3: apply LUT. Faithfully reproduces the reference's row_sel = b*c bug.
// pix = clip(trunc(dst*255), 0, 255). grid = (chunks, 24), block = 256.
// ---------------------------------------------------------------------------
__global__ __launch_bounds__(256) void hm_apply(const float* __restrict__ dst,
                                                const float* __restrict__ lut,
                                                float* __restrict__ out,
                                                int n4_per_row) {
    __shared__ float slut[BINS];
    const int bc = blockIdx.y;
    const int b = bc / C_N;
    const int c = bc - b * C_N;
    const int row = b * c;               // <-- preserved bug: b*c, not b*C+c
    const int t = threadIdx.x;

    slut[t] = lut[(size_t)row * BINS + t];
    __syncthreads();

    const float4* in4 = reinterpret_cast<const float4*>(dst) + (size_t)bc * n4_per_row;
    float4* out4 = reinterpret_cast<float4*>(out) + (size_t)bc * n4_per_row;
    const int gsz = gridDim.x * blockDim.x;

    #pragma unroll 4
    for (int i = blockIdx.x * blockDim.x + t; i < n4_per_row; i += gsz) {
        float4 v = in4[i];
        float4 o;
        o.x = slut[min(max((int)(v.x * 255.0f), 0), BINS - 1)];
        o.y = slut[min(max((int)(v.y * 255.0f), 0), BINS - 1)];
        o.z = slut[min(max((int)(v.z * 255.0f), 0), BINS - 1)];
        o.w = slut[min(max((int)(v.w * 255.0f), 0), BINS - 1)];
        out4[i] = o;
    }
}

extern "C" void kernel_launch(void* const* d_in, const int* in_sizes, int n_in,
                              void* d_out, int out_size, void* d_ws, size_t ws_size,
                              hipStream_t stream) {
    const float* dst  = (const float*)d_in[0];
    const float* refp = (const float*)d_in[1];
    float* out = (float*)d_out;

    const int total = in_sizes[0];          // 8*3*1024*1024
    const int hw = total / BC_N;            // 1048576
    const int n4 = hw >> 2;                 // 262144 float4 per row

    // workspace layout: [hist_dst 24x256 u32][hist_ref 24x256 u32][lut 24x256 f32]
    unsigned int* hist = (unsigned int*)d_ws;
    float* lut = (float*)((char*)d_ws + (size_t)2 * BC_N * BINS * sizeof(unsigned int));

    hipMemsetAsync(d_ws, 0, (size_t)2 * BC_N * BINS * sizeof(unsigned int), stream);

    dim3 hg(32, BC_N, 2);
    hm_hist<<<hg, dim3(256), 0, stream>>>(dst, refp, hist, n4);

    hm_table<<<dim3(BC_N), dim3(256), 0, stream>>>(hist, lut);

    dim3 ag(64, BC_N);
    hm_apply<<<ag, dim3(256), 0, stream>>>(dst, lut, out, n4);
}